// Round 1
// baseline (414.961 us; speedup 1.0000x reference)
//
#include <hip/hip_runtime.h>
#include <hip/hip_bf16.h>

#define NB2    1024      // 2*BATCH
#define FS1    10
#define FS2    25
#define FD     256
#define FH     256
#define MAXDEG 128

// ---------------- index building ----------------
__global__ void build_s1_kernel(const int* __restrict__ batch1,
                                const int* __restrict__ batch2,
                                const int* __restrict__ adj,
                                const int* __restrict__ col1,
                                int* __restrict__ nodes,
                                int* __restrict__ s1)
{
    int t = blockIdx.x * blockDim.x + threadIdx.x;
    if (t >= NB2 * FS1) return;
    int i = t / FS1;
    int node = (i < 512) ? batch1[i] : batch2[i - 512];
    if ((t % FS1) == 0) nodes[i] = node;
    s1[t] = adj[(long)node * MAXDEG + col1[t]];
}

__global__ void build_s2_kernel(const int* __restrict__ adj,
                                const int* __restrict__ s1,
                                const int* __restrict__ col2,
                                int* __restrict__ s2)
{
    int t = blockIdx.x * blockDim.x + threadIdx.x;
    if (t >= NB2 * FS1 * FS2) return;
    int i = t / FS2;
    s2[t] = adj[(long)s1[i] * MAXDEG + col2[t]];
}

// ---------------- group mean ----------------
// dst[g, d] = mean_j src[row(g,j), d], row = idx ? idx[g*F+j] : g*F+j
// launch: grid = G blocks, block = Dd threads
__global__ void mean_rows_kernel(const float* __restrict__ src, int ld,
                                 const int* __restrict__ idx,
                                 float* __restrict__ dst,
                                 int F, int Dd)
{
    int g = blockIdx.x;
    int d = threadIdx.x;
    float s = 0.f;
    for (int j = 0; j < F; ++j) {
        int r = idx ? idx[g * F + j] : g * F + j;
        s += src[(long)r * ld + d];
    }
    dst[(long)g * Dd + d] = s * (1.0f / F);
}

// ---------------- tiled fp32 GEMM with optional A row-gather ----------------
// C[bm..+64, coff+bn..+64] = act(A[idx?][.] @ B)
// grid: (N/64, M/64), block 256 threads, each thread 4x4.
#define BM 64
#define BN 64
#define BK 16
__global__ void gemm_kernel(const float* __restrict__ A,
                            const int* __restrict__ idxA, int lda,
                            const float* __restrict__ Bm, int ldb,
                            float* __restrict__ C, int ldc, int coff,
                            int K, int do_relu)
{
    __shared__ float As[BK][BM + 1];
    __shared__ float Bs[BK][BN + 1];
    const int bm = blockIdx.y * BM;
    const int bn = blockIdx.x * BN;
    const int tid = threadIdx.x;
    const int tx = tid & 15;   // 0..15 -> output col group
    const int ty = tid >> 4;   // 0..15 -> output row group

    float acc[4][4] = {};

    for (int k0 = 0; k0 < K; k0 += BK) {
        // A tile: 64 rows x 16 k. thread -> (r = l/16, c = l%16)
        #pragma unroll
        for (int l = tid; l < BM * BK; l += 256) {
            int r = l >> 4;
            int c = l & 15;
            int row = bm + r;
            int arow = idxA ? idxA[row] : row;
            As[c][r] = A[(long)arow * lda + k0 + c];
        }
        // B tile: 16 k x 64 n. thread -> (r = l/64, c = l%64)
        #pragma unroll
        for (int l = tid; l < BK * BN; l += 256) {
            int r = l >> 6;
            int c = l & 63;
            Bs[r][c] = Bm[(long)(k0 + r) * ldb + bn + c];
        }
        __syncthreads();
        #pragma unroll
        for (int kk = 0; kk < BK; ++kk) {
            float a[4], b[4];
            #pragma unroll
            for (int i = 0; i < 4; ++i) a[i] = As[kk][ty * 4 + i];
            #pragma unroll
            for (int j = 0; j < 4; ++j) b[j] = Bs[kk][tx * 4 + j];
            #pragma unroll
            for (int i = 0; i < 4; ++i)
                #pragma unroll
                for (int j = 0; j < 4; ++j)
                    acc[i][j] += a[i] * b[j];
        }
        __syncthreads();
    }

    #pragma unroll
    for (int i = 0; i < 4; ++i) {
        int row = bm + ty * 4 + i;
        #pragma unroll
        for (int j = 0; j < 4; ++j) {
            int col = coff + bn + tx * 4 + j;
            float v = acc[i][j];
            if (do_relu) v = fmaxf(v, 0.f);
            C[(long)row * ldc + col] = v;
        }
    }
}

// ---------------- row L2 normalize ----------------
// grid = 1024 rows, block = 256 threads (each handles 2 of 512 cols)
__global__ void l2norm_kernel(const float* __restrict__ in, float* __restrict__ out)
{
    int r = blockIdx.x;
    int t = threadIdx.x;
    float v0 = in[r * 512 + t];
    float v1 = in[r * 512 + 256 + t];
    float s = v0 * v0 + v1 * v1;
    #pragma unroll
    for (int o = 32; o > 0; o >>= 1) s += __shfl_down(s, o, 64);
    __shared__ float wsum[4];
    if ((t & 63) == 0) wsum[t >> 6] = s;
    __syncthreads();
    float tot = wsum[0] + wsum[1] + wsum[2] + wsum[3];
    float inv = rsqrtf(fmaxf(tot, 1e-12f));
    out[r * 512 + t] = v0 * inv;
    out[r * 512 + 256 + t] = v1 * inv;
}

extern "C" void kernel_launch(void* const* d_in, const int* in_sizes, int n_in,
                              void* d_out, int out_size, void* d_ws, size_t ws_size,
                              hipStream_t stream)
{
    const float* features = (const float*)d_in[0];
    const float* Ws1      = (const float*)d_in[1];
    const float* Wn1      = (const float*)d_in[2];
    const float* Ws2      = (const float*)d_in[3];
    const float* Wn2      = (const float*)d_in[4];
    const int*   adj      = (const int*)d_in[5];
    const int*   batch1   = (const int*)d_in[6];
    const int*   batch2   = (const int*)d_in[7];
    const int*   col1     = (const int*)d_in[8];
    const int*   col2     = (const int*)d_in[9];
    float* out = (float*)d_out;

    char* w = (char*)d_ws;
    auto alloc = [&](size_t bytes) {
        char* p = w;
        w += (bytes + 255) & ~(size_t)255;
        return p;
    };
    int*   nodes = (int*)alloc((size_t)NB2 * 4);
    int*   s1    = (int*)alloc((size_t)NB2 * FS1 * 4);
    int*   s2    = (int*)alloc((size_t)NB2 * FS1 * FS2 * 4);
    float* nm1   = (float*)alloc((size_t)NB2 * FD * 4);                 // mean of h1 per node
    float* nm2   = (float*)alloc((size_t)NB2 * FS1 * FD * 4);           // mean of h2 per s1 node
    float* h0n   = (float*)alloc((size_t)NB2 * 2 * FH * 4);             // [1024,512]
    float* h1n   = (float*)alloc((size_t)NB2 * FS1 * 2 * FH * 4);       // [10240,512]
    float* ml2   = (float*)alloc((size_t)NB2 * 2 * FH * 4);             // layer2 neighbor mean
    float* opre  = (float*)alloc((size_t)NB2 * 2 * FH * 4);             // pre-normalize output

    // 1. sampling indices
    build_s1_kernel<<<(NB2 * FS1 + 255) / 256, 256, 0, stream>>>(batch1, batch2, adj, col1, nodes, s1);
    build_s2_kernel<<<(NB2 * FS1 * FS2 + 255) / 256, 256, 0, stream>>>(adj, s1, col2, s2);

    // 2. layer-1 neighbor means
    mean_rows_kernel<<<NB2 * FS1, FD, 0, stream>>>(features, FD, s2, nm2, FS2, FD);
    mean_rows_kernel<<<NB2, FD, 0, stream>>>(features, FD, s1, nm1, FS1, FD);

    // 3. layer-1 GEMMs (relu)
    {
        dim3 g1(FH / BN, (NB2 * FS1) / BM);   // (4, 160)
        gemm_kernel<<<g1, 256, 0, stream>>>(features, s1, FD, Ws1, FH, h1n, 2 * FH, 0,  FD, 1);
        gemm_kernel<<<g1, 256, 0, stream>>>(nm2, nullptr, FD, Wn1, FH, h1n, 2 * FH, FH, FD, 1);
        dim3 g0(FH / BN, NB2 / BM);           // (4, 16)
        gemm_kernel<<<g0, 256, 0, stream>>>(features, nodes, FD, Ws1, FH, h0n, 2 * FH, 0,  FD, 1);
        gemm_kernel<<<g0, 256, 0, stream>>>(nm1, nullptr, FD, Wn1, FH, h0n, 2 * FH, FH, FD, 1);
    }

    // 4. layer-2 neighbor mean over h1_new groups of 10
    mean_rows_kernel<<<NB2, 2 * FH, 0, stream>>>(h1n, 2 * FH, nullptr, ml2, FS1, 2 * FH);

    // 5. layer-2 GEMMs (identity)
    {
        dim3 g0(FH / BN, NB2 / BM);           // (4, 16)
        gemm_kernel<<<g0, 256, 0, stream>>>(h0n, nullptr, 2 * FH, Ws2, FH, opre, 2 * FH, 0,  2 * FH, 0);
        gemm_kernel<<<g0, 256, 0, stream>>>(ml2, nullptr, 2 * FH, Wn2, FH, opre, 2 * FH, FH, 2 * FH, 0);
    }

    // 6. L2 normalize -> output
    l2norm_kernel<<<NB2, 256, 0, stream>>>(opre, out);
}

// Round 4
// 188.662 us; speedup vs baseline: 2.1995x; 2.1995x over previous
//
#include <hip/hip_runtime.h>
#include <hip/hip_bf16.h>

#define NB2    1024      // 2*BATCH
#define FS1    10
#define FS2    25
#define FD     256
#define FH     256
#define MAXDEG 128

typedef __attribute__((ext_vector_type(8))) short bf16x8;
typedef __attribute__((ext_vector_type(4))) float f32x4;

__device__ inline ushort f2bf(float f) {
    union { float f; unsigned u; } v; v.f = f;
    unsigned u = v.u;
    unsigned r = (u + 0x7FFFu + ((u >> 16) & 1u)) >> 16;   // round-to-nearest-even
    return (ushort)r;
}
__device__ inline float bf2f(ushort h) {
    union { unsigned u; float f; } v; v.u = ((unsigned)h) << 16;
    return v.f;
}

// ---------------- index building ----------------
__global__ void build_s1_kernel(const int* __restrict__ batch1,
                                const int* __restrict__ batch2,
                                const int* __restrict__ adj,
                                const int* __restrict__ col1,
                                int* __restrict__ nodes,
                                int* __restrict__ s1)
{
    int t = blockIdx.x * blockDim.x + threadIdx.x;
    if (t >= NB2 * FS1) return;
    int i = t / FS1;
    int node = (i < 512) ? batch1[i] : batch2[i - 512];
    if ((t % FS1) == 0) nodes[i] = node;
    s1[t] = adj[(long)node * MAXDEG + col1[t]];
}

__global__ void build_s2_kernel(const int* __restrict__ adj,
                                const int* __restrict__ s1,
                                const int* __restrict__ col2,
                                int* __restrict__ s2)
{
    int t = blockIdx.x * blockDim.x + threadIdx.x;
    if (t >= NB2 * FS1 * FS2) return;
    int i = t / FS2;
    s2[t] = adj[(long)s1[i] * MAXDEG + col2[t]];
}

// ---------------- weight transpose + bf16 cast ----------------
// Wt[n*K + k] = bf16(W[k*N + n])
__global__ void wt_kernel(const float* __restrict__ W, ushort* __restrict__ Wt,
                          int K, int N)
{
    int t = blockIdx.x * blockDim.x + threadIdx.x;
    if (t >= K * N) return;
    int k = t / N, n = t % N;
    Wt[(long)n * K + k] = f2bf(W[t]);
}

// ---------------- group mean: fp32 gather src, dim 256, bf16 out ----------------
// wave per group; 64 lanes x float4 = 256 cols
__global__ void mean_f32_kernel(const float* __restrict__ src,
                                const int* __restrict__ idx,
                                ushort* __restrict__ dst,
                                int F, int G)
{
    int g = blockIdx.x * 4 + (threadIdx.x >> 6);
    if (g >= G) return;
    int l = threadIdx.x & 63;
    float4 acc = make_float4(0.f, 0.f, 0.f, 0.f);
    const int* ip = idx + (long)g * F;
    for (int j = 0; j < F; ++j) {
        int r = ip[j];
        const float4 v = *((const float4*)(src + (long)r * FD) + l);
        acc.x += v.x; acc.y += v.y; acc.z += v.z; acc.w += v.w;
    }
    float s = 1.0f / F;
    uint2 o;
    o.x = (unsigned)f2bf(acc.x * s) | ((unsigned)f2bf(acc.y * s) << 16);
    o.y = (unsigned)f2bf(acc.z * s) | ((unsigned)f2bf(acc.w * s) << 16);
    *((uint2*)(dst + (long)g * FD) + l) = o;
}

// ---------------- group mean: bf16 contiguous src, dim 512, bf16 out ----------------
// wave per group; 64 lanes x 8 bf16 = 512 cols; groups of F consecutive rows
__global__ void mean_bf16_kernel(const ushort* __restrict__ src,
                                 ushort* __restrict__ dst,
                                 int F, int G)
{
    int g = blockIdx.x * 4 + (threadIdx.x >> 6);
    if (g >= G) return;
    int l = threadIdx.x & 63;
    float acc[8] = {};
    for (int j = 0; j < F; ++j) {
        uint4 v = *((const uint4*)(src + ((long)g * F + j) * 512) + l);
        unsigned w[4] = { v.x, v.y, v.z, v.w };
        #pragma unroll
        for (int q = 0; q < 4; ++q) {
            acc[2 * q]     += bf2f((ushort)(w[q] & 0xFFFF));
            acc[2 * q + 1] += bf2f((ushort)(w[q] >> 16));
        }
    }
    float s = 1.0f / F;
    uint4 o;
    unsigned* ow = (unsigned*)&o;
    #pragma unroll
    for (int q = 0; q < 4; ++q)
        ow[q] = (unsigned)f2bf(acc[2 * q] * s) | ((unsigned)f2bf(acc[2 * q + 1] * s) << 16);
    *((uint4*)(dst + (long)g * 512) + l) = o;
}

// ---------------- MFMA GEMM, no LDS ----------------
// Block = 256 thr = 4 waves. Block handles 64 M-rows; wave w handles N-strip
// [w*64, w*64+64) of the 256 output cols. C[bm+., coff + w*64 + .].
// A: row-major [.,K]; if a_f32: fp32 with optional row-gather idxA, convert in-reg.
//    else bf16 contiguous. Bt: bf16 [256][K] (pre-transposed weights).
// k-mapping: lane l holds k = 8*(l>>4)..+7 for both A and B (same bijection ->
// correct for any internal MFMA k-order).
template <int A_F32, int RELU, int C_F32>
__global__ void mfma_gemm_kernel(const void* __restrict__ Ap,
                                 const int* __restrict__ idxA, int lda,
                                 const ushort* __restrict__ Bt,
                                 void* __restrict__ Cp, int ldc, int coff,
                                 int K)
{
    const int wave = threadIdx.x >> 6;
    const int l    = threadIdx.x & 63;
    const int m16  = l & 15;
    const int g    = l >> 4;
    const int bm   = blockIdx.x * 64;

    f32x4 acc[4][4];
    #pragma unroll
    for (int i = 0; i < 4; ++i)
        #pragma unroll
        for (int j = 0; j < 4; ++j)
            acc[i][j] = (f32x4){0.f, 0.f, 0.f, 0.f};

    // resolve gathered rows once
    int rowidx[4];
    #pragma unroll
    for (int i = 0; i < 4; ++i) {
        int r = bm + i * 16 + m16;
        rowidx[i] = idxA ? idxA[r] : r;
    }

    for (int k0 = 0; k0 < K; k0 += 32) {
        bf16x8 a[4], b[4];
        #pragma unroll
        for (int i = 0; i < 4; ++i) {
            if (A_F32) {
                const float* p = (const float*)Ap + (long)rowidx[i] * lda + k0 + g * 8;
                float4 v0 = *(const float4*)p;
                float4 v1 = *(const float4*)(p + 4);
                bf16x8 t;
                t[0] = (short)f2bf(v0.x); t[1] = (short)f2bf(v0.y);
                t[2] = (short)f2bf(v0.z); t[3] = (short)f2bf(v0.w);
                t[4] = (short)f2bf(v1.x); t[5] = (short)f2bf(v1.y);
                t[6] = (short)f2bf(v1.z); t[7] = (short)f2bf(v1.w);
                a[i] = t;
            } else {
                const ushort* p = (const ushort*)Ap + (long)rowidx[i] * lda + k0 + g * 8;
                a[i] = *(const bf16x8*)p;
            }
            int n = wave * 64 + i * 16 + m16;
            b[i] = *(const bf16x8*)(Bt + (long)n * K + k0 + g * 8);
        }
        #pragma unroll
        for (int i = 0; i < 4; ++i)
            #pragma unroll
            for (int j = 0; j < 4; ++j)
                acc[i][j] = __builtin_amdgcn_mfma_f32_16x16x32_bf16(a[i], b[j], acc[i][j], 0, 0, 0);
    }

    // store: D col = lane&15, row = (lane>>4)*4 + reg   [m89-verified]
    #pragma unroll
    for (int i = 0; i < 4; ++i) {
        #pragma unroll
        for (int j = 0; j < 4; ++j) {
            #pragma unroll
            for (int r = 0; r < 4; ++r) {
                int row = bm + i * 16 + g * 4 + r;
                int col = coff + wave * 64 + j * 16 + m16;
                float v = acc[i][j][r];
                if (RELU) v = fmaxf(v, 0.f);
                if (C_F32) ((float*)Cp)[(long)row * ldc + col] = v;
                else       ((ushort*)Cp)[(long)row * ldc + col] = f2bf(v);
            }
        }
    }
}

// ---------------- row L2 normalize ----------------
__global__ void l2norm_kernel(const float* __restrict__ in, float* __restrict__ out)
{
    int r = blockIdx.x;
    int t = threadIdx.x;
    float v0 = in[r * 512 + t];
    float v1 = in[r * 512 + 256 + t];
    float s = v0 * v0 + v1 * v1;
    #pragma unroll
    for (int o = 32; o > 0; o >>= 1) s += __shfl_down(s, o, 64);
    __shared__ float wsum[4];
    if ((t & 63) == 0) wsum[t >> 6] = s;
    __syncthreads();
    float tot = wsum[0] + wsum[1] + wsum[2] + wsum[3];
    float inv = rsqrtf(fmaxf(tot, 1e-12f));
    out[r * 512 + t] = v0 * inv;
    out[r * 512 + 256 + t] = v1 * inv;
}

extern "C" void kernel_launch(void* const* d_in, const int* in_sizes, int n_in,
                              void* d_out, int out_size, void* d_ws, size_t ws_size,
                              hipStream_t stream)
{
    const float* features = (const float*)d_in[0];
    const float* Ws1      = (const float*)d_in[1];
    const float* Wn1      = (const float*)d_in[2];
    const float* Ws2      = (const float*)d_in[3];
    const float* Wn2      = (const float*)d_in[4];
    const int*   adj      = (const int*)d_in[5];
    const int*   batch1   = (const int*)d_in[6];
    const int*   batch2   = (const int*)d_in[7];
    const int*   col1     = (const int*)d_in[8];
    const int*   col2     = (const int*)d_in[9];
    float* out = (float*)d_out;

    char* w = (char*)d_ws;
    auto alloc = [&](size_t bytes) {
        char* p = w;
        w += (bytes + 255) & ~(size_t)255;
        return p;
    };
    int*    nodes = (int*)alloc((size_t)NB2 * 4);
    int*    s1    = (int*)alloc((size_t)NB2 * FS1 * 4);
    int*    s2    = (int*)alloc((size_t)NB2 * FS1 * FS2 * 4);
    ushort* nm1   = (ushort*)alloc((size_t)NB2 * FD * 2);            // bf16 [1024,256]
    ushort* nm2   = (ushort*)alloc((size_t)NB2 * FS1 * FD * 2);      // bf16 [10240,256]
    ushort* h0n   = (ushort*)alloc((size_t)NB2 * 512 * 2);           // bf16 [1024,512]
    ushort* h1n   = (ushort*)alloc((size_t)NB2 * FS1 * 512 * 2);     // bf16 [10240,512]
    ushort* ml2   = (ushort*)alloc((size_t)NB2 * 512 * 2);           // bf16 [1024,512]
    float*  opre  = (float*)alloc((size_t)NB2 * 512 * 4);            // fp32 [1024,512]
    ushort* Wt_s1 = (ushort*)alloc((size_t)FD * FH * 2);             // [256][256] (n-major)
    ushort* Wt_n1 = (ushort*)alloc((size_t)FD * FH * 2);
    ushort* Wt_s2 = (ushort*)alloc((size_t)512 * FH * 2);            // [256][512] n-major
    ushort* Wt_n2 = (ushort*)alloc((size_t)512 * FH * 2);

    // 0. weight transpose+cast (Wt[n][k])
    wt_kernel<<<(FD * FH + 255) / 256, 256, 0, stream>>>(Ws1, Wt_s1, FD, FH);
    wt_kernel<<<(FD * FH + 255) / 256, 256, 0, stream>>>(Wn1, Wt_n1, FD, FH);
    wt_kernel<<<(512 * FH + 255) / 256, 256, 0, stream>>>(Ws2, Wt_s2, 512, FH);
    wt_kernel<<<(512 * FH + 255) / 256, 256, 0, stream>>>(Wn2, Wt_n2, 512, FH);

    // 1. sampling indices
    build_s1_kernel<<<(NB2 * FS1 + 255) / 256, 256, 0, stream>>>(batch1, batch2, adj, col1, nodes, s1);
    build_s2_kernel<<<(NB2 * FS1 * FS2 + 255) / 256, 256, 0, stream>>>(adj, s1, col2, s2);

    // 2. layer-1 neighbor means (fp32 accumulate, single rounding to bf16)
    mean_f32_kernel<<<(NB2 * FS1) / 4, 256, 0, stream>>>(features, s2, nm2, FS2, NB2 * FS1);
    mean_f32_kernel<<<NB2 / 4, 256, 0, stream>>>(features, s1, nm1, FS1, NB2);

    // 3. layer-1 GEMMs (relu, bf16 out)
    mfma_gemm_kernel<1, 1, 0><<<(NB2 * FS1) / 64, 256, 0, stream>>>(
        features, s1, FD, Wt_s1, h1n, 512, 0, FD);
    mfma_gemm_kernel<0, 1, 0><<<(NB2 * FS1) / 64, 256, 0, stream>>>(
        nm2, nullptr, FD, Wt_n1, h1n, 512, FH, FD);
    mfma_gemm_kernel<1, 1, 0><<<NB2 / 64, 256, 0, stream>>>(
        features, nodes, FD, Wt_s1, h0n, 512, 0, FD);
    mfma_gemm_kernel<0, 1, 0><<<NB2 / 64, 256, 0, stream>>>(
        nm1, nullptr, FD, Wt_n1, h0n, 512, FH, FD);

    // 4. layer-2 neighbor mean (groups of 10 consecutive h1n rows)
    mean_bf16_kernel<<<NB2 / 4, 256, 0, stream>>>(h1n, ml2, FS1, NB2);

    // 5. layer-2 GEMMs (identity, fp32 out)
    mfma_gemm_kernel<0, 0, 1><<<NB2 / 64, 256, 0, stream>>>(
        h0n, nullptr, 512, Wt_s2, opre, 512, 0, 512);
    mfma_gemm_kernel<0, 0, 1><<<NB2 / 64, 256, 0, stream>>>(
        ml2, nullptr, 512, Wt_n2, opre, 512, FH, 512);

    // 6. L2 normalize -> output
    l2norm_kernel<<<NB2, 256, 0, stream>>>(opre, out);
}

// Round 6
// 149.132 us; speedup vs baseline: 2.7825x; 1.2651x over previous
//
#include <hip/hip_runtime.h>
#include <hip/hip_bf16.h>

#define NB2    1024      // 2*BATCH
#define FS1    10
#define FS2    25
#define FD     256
#define FH     256
#define MAXDEG 128

typedef __attribute__((ext_vector_type(8))) short bf16x8;
typedef __attribute__((ext_vector_type(4))) float f32x4;

__device__ inline ushort f2bf(float f) {
    union { float f; unsigned u; } v; v.f = f;
    unsigned u = v.u;
    unsigned r = (u + 0x7FFFu + ((u >> 16) & 1u)) >> 16;   // round-to-nearest-even
    return (ushort)r;
}
__device__ inline float bf2f(ushort h) {
    union { unsigned u; float f; } v; v.u = ((unsigned)h) << 16;
    return v.f;
}

// ---------------- fused prep: weight transpose+cast AND sampling ----------------
// blocks [0,1536): Wt[n*K+k] = bf16(W[k*N+n]) for the 4 weight mats (N=256 all)
// blocks [1536,2536): t2 in [0,256000): build s1 (recomputed per thread) and s2
__global__ void prep_kernel(const float* __restrict__ Ws1, const float* __restrict__ Wn1,
                            const float* __restrict__ Ws2, const float* __restrict__ Wn2,
                            ushort* __restrict__ Wt_s1, ushort* __restrict__ Wt_n1,
                            ushort* __restrict__ Wt_s2, ushort* __restrict__ Wt_n2,
                            const int* __restrict__ batch1, const int* __restrict__ batch2,
                            const int* __restrict__ adj,
                            const int* __restrict__ col1, const int* __restrict__ col2,
                            int* __restrict__ nodes, int* __restrict__ s1,
                            int* __restrict__ s2)
{
    int b = blockIdx.x;
    if (b < 1536) {
        int t = b * 256 + threadIdx.x;          // [0, 393216)
        const float* W; ushort* Wt; int K; int base;
        if (t < 131072) {
            K = 256;
            if (t < 65536) { W = Ws1; Wt = Wt_s1; base = 0; }
            else           { W = Wn1; Wt = Wt_n1; base = 65536; }
        } else {
            K = 512;
            if (t < 262144) { W = Ws2; Wt = Wt_s2; base = 131072; }
            else            { W = Wn2; Wt = Wt_n2; base = 262144; }
        }
        int tt = t - base;
        int k = tt >> 8;          // N = 256
        int n = tt & 255;
        Wt[(long)n * K + k] = f2bf(W[tt]);
    } else {
        int t2 = (b - 1536) * 256 + threadIdx.x;   // [0, 256000)
        int i  = t2 / FS2;                          // s1 index [0,10240)
        int ns = i / FS1;                           // node slot [0,1024)
        int node = (ns < 512) ? batch1[ns] : batch2[ns - 512];
        int s1v = adj[(long)node * MAXDEG + col1[i]];
        s2[t2] = adj[(long)s1v * MAXDEG + col2[t2]];
        if (t2 - i * FS2 == 0) {
            s1[i] = s1v;
            if (i - ns * FS1 == 0) nodes[ns] = node;
        }
    }
}

// ---------------- fused gather means (deep MLP) ----------------
// wave per group; 64 lanes x float4 = 256 cols; F rows gathered via idx.
// Indices preloaded; row loads issued in bursts of 8 into 4 round-robin accs.
template<int F>
__device__ __forceinline__ void mean_body(const float* __restrict__ src,
                                          const int* __restrict__ idx,
                                          ushort* __restrict__ dst,
                                          int g, int l)
{
    const int* ip = idx + (long)g * F;
    int r[F];
    #pragma unroll
    for (int j = 0; j < F; ++j) r[j] = ip[j];

    float4 acc[4];
    #pragma unroll
    for (int q = 0; q < 4; ++q) acc[q] = make_float4(0.f, 0.f, 0.f, 0.f);

    #pragma unroll
    for (int j0 = 0; j0 < F; j0 += 8) {
        float4 v[8];
        #pragma unroll
        for (int u = 0; u < 8; ++u)
            if (j0 + u < F)
                v[u] = *((const float4*)(src + (long)r[j0 + u] * FD) + l);
        #pragma unroll
        for (int u = 0; u < 8; ++u)
            if (j0 + u < F) {
                int q = u & 3;
                acc[q].x += v[u].x; acc[q].y += v[u].y;
                acc[q].z += v[u].z; acc[q].w += v[u].w;
            }
    }
    float s = 1.0f / F;
    float sx = (acc[0].x + acc[1].x + acc[2].x + acc[3].x) * s;
    float sy = (acc[0].y + acc[1].y + acc[2].y + acc[3].y) * s;
    float sz = (acc[0].z + acc[1].z + acc[2].z + acc[3].z) * s;
    float sw = (acc[0].w + acc[1].w + acc[2].w + acc[3].w) * s;
    uint2 o;
    o.x = (unsigned)f2bf(sx) | ((unsigned)f2bf(sy) << 16);
    o.y = (unsigned)f2bf(sz) | ((unsigned)f2bf(sw) << 16);
    *((uint2*)(dst + (long)g * FD) + l) = o;
}

// blocks [0,2560): s2-mean (F=25, G=10240) -> nm2 ; [2560,2816): s1-mean (F=10) -> nm1
__global__ void means_kernel(const float* __restrict__ features,
                             const int* __restrict__ s2, const int* __restrict__ s1,
                             ushort* __restrict__ nm2, ushort* __restrict__ nm1)
{
    int wb = blockIdx.x;
    int wave = threadIdx.x >> 6;
    int l = threadIdx.x & 63;
    if (wb < 2560) mean_body<FS2>(features, s2, nm2, wb * 4 + wave, l);
    else           mean_body<FS1>(features, s1, nm1, (wb - 2560) * 4 + wave, l);
}

// ---------------- layer-1 fused MFMA GEMM (M-split waves, no LDS) ----------------
// K=256, N=256 per sub-GEMM. Block = 4 waves x 16 rows = 64 M-rows.
// Wave owns rows [r0, r0+16), all 256 cols -> each wave reads its OWN A rows once.
// b<160: h1 self (features gather via s1, fp32); b<320: h1 neigh (nm2 bf16);
// b<336: h0 self (features gather via nodes); b<352: h0 neigh (nm1 bf16).
__global__ void l1gemm_kernel(const float* __restrict__ features,
                              const ushort* __restrict__ nm2, const ushort* __restrict__ nm1,
                              const int* __restrict__ s1, const int* __restrict__ nodes,
                              const ushort* __restrict__ Wt_s1, const ushort* __restrict__ Wt_n1,
                              ushort* __restrict__ h1n, ushort* __restrict__ h0n)
{
    int b = blockIdx.x;
    const int wave = threadIdx.x >> 6;
    const int l    = threadIdx.x & 63;
    const int m16  = l & 15;
    const int g    = l >> 4;

    int self, bm, coff;
    const ushort* An = nullptr;
    const int* idx = nullptr;
    const ushort* Bt;
    ushort* C;
    if (b < 160)      { self = 1; idx = s1;    bm = b * 64;         C = h1n; Bt = Wt_s1; coff = 0; }
    else if (b < 320) { self = 0; An  = nm2;   bm = (b - 160) * 64; C = h1n; Bt = Wt_n1; coff = 256; }
    else if (b < 336) { self = 1; idx = nodes; bm = (b - 320) * 64; C = h0n; Bt = Wt_s1; coff = 0; }
    else              { self = 0; An  = nm1;   bm = (b - 336) * 64; C = h0n; Bt = Wt_n1; coff = 256; }

    const int r0  = bm + wave * 16;
    const int row = r0 + m16;
    const long arow = self ? (long)idx[row] : (long)row;

    f32x4 acc[16];
    #pragma unroll
    for (int j = 0; j < 16; ++j) acc[j] = (f32x4){0.f, 0.f, 0.f, 0.f};

    for (int k0 = 0; k0 < 256; k0 += 32) {
        bf16x8 a;
        if (self) {
            const float* p = features + arow * FD + k0 + g * 8;
            float4 v0 = *(const float4*)p;
            float4 v1 = *(const float4*)(p + 4);
            a[0] = (short)f2bf(v0.x); a[1] = (short)f2bf(v0.y);
            a[2] = (short)f2bf(v0.z); a[3] = (short)f2bf(v0.w);
            a[4] = (short)f2bf(v1.x); a[5] = (short)f2bf(v1.y);
            a[6] = (short)f2bf(v1.z); a[7] = (short)f2bf(v1.w);
        } else {
            a = *(const bf16x8*)(An + arow * FD + k0 + g * 8);
        }
        #pragma unroll
        for (int j = 0; j < 16; ++j) {
            bf16x8 bf = *(const bf16x8*)(Bt + (long)(j * 16 + m16) * 256 + k0 + g * 8);
            acc[j] = __builtin_amdgcn_mfma_f32_16x16x32_bf16(a, bf, acc[j], 0, 0, 0);
        }
    }

    // D: col = lane&15, row = (lane>>4)*4 + reg  [m89-verified]
    #pragma unroll
    for (int j = 0; j < 16; ++j) {
        #pragma unroll
        for (int r = 0; r < 4; ++r) {
            int rr = r0 + g * 4 + r;
            int cc = coff + j * 16 + m16;
            C[(long)rr * 512 + cc] = f2bf(fmaxf(acc[j][r], 0.f));
        }
    }
}

// ---------------- layer-2 neighbor mean (groups of 10 consecutive h1n rows) ----
__global__ void mean_bf16_kernel(const ushort* __restrict__ src,
                                 ushort* __restrict__ dst,
                                 int F, int G)
{
    int g = blockIdx.x * 4 + (threadIdx.x >> 6);
    if (g >= G) return;
    int l = threadIdx.x & 63;
    float acc[8] = {};
    for (int j = 0; j < F; ++j) {
        uint4 v = *((const uint4*)(src + ((long)g * F + j) * 512) + l);
        unsigned w[4] = { v.x, v.y, v.z, v.w };
        #pragma unroll
        for (int q = 0; q < 4; ++q) {
            acc[2 * q]     += bf2f((ushort)(w[q] & 0xFFFF));
            acc[2 * q + 1] += bf2f((ushort)(w[q] >> 16));
        }
    }
    float s = 1.0f / F;
    uint4 o;
    unsigned* ow = (unsigned*)&o;
    #pragma unroll
    for (int q = 0; q < 4; ++q)
        ow[q] = (unsigned)f2bf(acc[2 * q] * s) | ((unsigned)f2bf(acc[2 * q + 1] * s) << 16);
    *((uint4*)(dst + (long)g * 512) + l) = o;
}

// ---------------- layer-2 fused MFMA GEMM (K=512, fp32 out) ----------------
// b<16: self (h0n @ Wt_s2, coff 0); b>=16: neigh (ml2 @ Wt_n2, coff 256)
__global__ void l2gemm_kernel(const ushort* __restrict__ h0n, const ushort* __restrict__ ml2,
                              const ushort* __restrict__ Wt_s2, const ushort* __restrict__ Wt_n2,
                              float* __restrict__ opre)
{
    int b = blockIdx.x;
    const int wave = threadIdx.x >> 6;
    const int l    = threadIdx.x & 63;
    const int m16  = l & 15;
    const int g    = l >> 4;

    const ushort* A; const ushort* Bt; int coff;
    if (b < 16) { A = h0n; Bt = Wt_s2; coff = 0; }
    else        { A = ml2; Bt = Wt_n2; coff = 256; b -= 16; }

    const int r0  = b * 64 + wave * 16;
    const int row = r0 + m16;

    f32x4 acc[16];
    #pragma unroll
    for (int j = 0; j < 16; ++j) acc[j] = (f32x4){0.f, 0.f, 0.f, 0.f};

    for (int k0 = 0; k0 < 512; k0 += 32) {
        bf16x8 a = *(const bf16x8*)(A + (long)row * 512 + k0 + g * 8);
        #pragma unroll
        for (int j = 0; j < 16; ++j) {
            bf16x8 bf = *(const bf16x8*)(Bt + (long)(j * 16 + m16) * 512 + k0 + g * 8);
            acc[j] = __builtin_amdgcn_mfma_f32_16x16x32_bf16(a, bf, acc[j], 0, 0, 0);
        }
    }

    #pragma unroll
    for (int j = 0; j < 16; ++j) {
        #pragma unroll
        for (int r = 0; r < 4; ++r) {
            int rr = r0 + g * 4 + r;
            int cc = coff + j * 16 + m16;
            opre[(long)rr * 512 + cc] = acc[j][r];
        }
    }
}

// ---------------- row L2 normalize ----------------
__global__ void l2norm_kernel(const float* __restrict__ in, float* __restrict__ out)
{
    int r = blockIdx.x;
    int t = threadIdx.x;
    float v0 = in[r * 512 + t];
    float v1 = in[r * 512 + 256 + t];
    float s = v0 * v0 + v1 * v1;
    #pragma unroll
    for (int o = 32; o > 0; o >>= 1) s += __shfl_down(s, o, 64);
    __shared__ float wsum[4];
    if ((t & 63) == 0) wsum[t >> 6] = s;
    __syncthreads();
    float tot = wsum[0] + wsum[1] + wsum[2] + wsum[3];
    float inv = rsqrtf(fmaxf(tot, 1e-12f));
    out[r * 512 + t] = v0 * inv;
    out[r * 512 + 256 + t] = v1 * inv;
}

extern "C" void kernel_launch(void* const* d_in, const int* in_sizes, int n_in,
                              void* d_out, int out_size, void* d_ws, size_t ws_size,
                              hipStream_t stream)
{
    const float* features = (const float*)d_in[0];
    const float* Ws1      = (const float*)d_in[1];
    const float* Wn1      = (const float*)d_in[2];
    const float* Ws2      = (const float*)d_in[3];
    const float* Wn2      = (const float*)d_in[4];
    const int*   adj      = (const int*)d_in[5];
    const int*   batch1   = (const int*)d_in[6];
    const int*   batch2   = (const int*)d_in[7];
    const int*   col1     = (const int*)d_in[8];
    const int*   col2     = (const int*)d_in[9];
    float* out = (float*)d_out;

    char* w = (char*)d_ws;
    auto alloc = [&](size_t bytes) {
        char* p = w;
        w += (bytes + 255) & ~(size_t)255;
        return p;
    };
    int*    nodes = (int*)alloc((size_t)NB2 * 4);
    int*    s1    = (int*)alloc((size_t)NB2 * FS1 * 4);
    int*    s2    = (int*)alloc((size_t)NB2 * FS1 * FS2 * 4);
    ushort* nm1   = (ushort*)alloc((size_t)NB2 * FD * 2);            // bf16 [1024,256]
    ushort* nm2   = (ushort*)alloc((size_t)NB2 * FS1 * FD * 2);      // bf16 [10240,256]
    ushort* h0n   = (ushort*)alloc((size_t)NB2 * 512 * 2);           // bf16 [1024,512]
    ushort* h1n   = (ushort*)alloc((size_t)NB2 * FS1 * 512 * 2);     // bf16 [10240,512]
    ushort* ml2   = (ushort*)alloc((size_t)NB2 * 512 * 2);           // bf16 [1024,512]
    float*  opre  = (float*)alloc((size_t)NB2 * 512 * 4);            // fp32 [1024,512]
    ushort* Wt_s1 = (ushort*)alloc((size_t)FD * FH * 2);             // [256][256] n-major
    ushort* Wt_n1 = (ushort*)alloc((size_t)FD * FH * 2);
    ushort* Wt_s2 = (ushort*)alloc((size_t)512 * FH * 2);            // [256][512] n-major
    ushort* Wt_n2 = (ushort*)alloc((size_t)512 * FH * 2);

    // 1. prep: weight transpose/cast + sampling (s1, s2, nodes)
    prep_kernel<<<2536, 256, 0, stream>>>(Ws1, Wn1, Ws2, Wn2,
                                          Wt_s1, Wt_n1, Wt_s2, Wt_n2,
                                          batch1, batch2, adj, col1, col2,
                                          nodes, s1, s2);

    // 2. layer-1 gather means (fp32 accumulate, bf16 out)
    means_kernel<<<2816, 256, 0, stream>>>(features, s2, s1, nm2, nm1);

    // 3. layer-1 GEMMs (relu, bf16 out) — one fused launch, 352 blocks
    l1gemm_kernel<<<352, 256, 0, stream>>>(features, nm2, nm1, s1, nodes,
                                           Wt_s1, Wt_n1, h1n, h0n);

    // 4. layer-2 neighbor mean (groups of 10 consecutive h1n rows)
    mean_bf16_kernel<<<NB2 / 4, 256, 0, stream>>>(h1n, ml2, FS1, NB2);

    // 5. layer-2 GEMMs (identity, fp32 out) — one fused launch, 32 blocks
    l2gemm_kernel<<<32, 256, 0, stream>>>(h0n, ml2, Wt_s2, Wt_n2, opre);

    // 6. L2 normalize -> output
    l2norm_kernel<<<NB2, 256, 0, stream>>>(opre, out);
}

// Round 7
// 98.257 us; speedup vs baseline: 4.2232x; 1.5178x over previous
//
#include <hip/hip_runtime.h>
#include <hip/hip_bf16.h>

#define NB2    1024      // 2*BATCH
#define FS1    10
#define FS2    25
#define FD     256
#define FH     256
#define MAXDEG 128

typedef __attribute__((ext_vector_type(8))) short bf16x8;
typedef __attribute__((ext_vector_type(4))) float f32x4;

__device__ inline ushort f2bf(float f) {
    union { float f; unsigned u; } v; v.f = f;
    unsigned u = v.u;
    unsigned r = (u + 0x7FFFu + ((u >> 16) & 1u)) >> 16;   // round-to-nearest-even
    return (ushort)r;
}
__device__ inline float bf2f(ushort h) {
    union { unsigned u; float f; } v; v.u = ((unsigned)h) << 16;
    return v.f;
}

// ---------------- fused prep: weight transpose+cast AND sampling ----------------
__global__ void prep_kernel(const float* __restrict__ Ws1, const float* __restrict__ Wn1,
                            const float* __restrict__ Ws2, const float* __restrict__ Wn2,
                            ushort* __restrict__ Wt_s1, ushort* __restrict__ Wt_n1,
                            ushort* __restrict__ Wt_s2, ushort* __restrict__ Wt_n2,
                            const int* __restrict__ batch1, const int* __restrict__ batch2,
                            const int* __restrict__ adj,
                            const int* __restrict__ col1, const int* __restrict__ col2,
                            int* __restrict__ nodes, int* __restrict__ s1,
                            int* __restrict__ s2)
{
    int b = blockIdx.x;
    if (b < 1536) {
        int t = b * 256 + threadIdx.x;          // [0, 393216)
        const float* W; ushort* Wt; int K; int base;
        if (t < 131072) {
            K = 256;
            if (t < 65536) { W = Ws1; Wt = Wt_s1; base = 0; }
            else           { W = Wn1; Wt = Wt_n1; base = 65536; }
        } else {
            K = 512;
            if (t < 262144) { W = Ws2; Wt = Wt_s2; base = 131072; }
            else            { W = Wn2; Wt = Wt_n2; base = 262144; }
        }
        int tt = t - base;
        int k = tt >> 8;          // N = 256
        int n = tt & 255;
        Wt[(long)n * K + k] = f2bf(W[tt]);
    } else {
        int t2 = (b - 1536) * 256 + threadIdx.x;   // [0, 256000)
        int i  = t2 / FS2;                          // s1 index [0,10240)
        int ns = i / FS1;                           // node slot [0,1024)
        int node = (ns < 512) ? batch1[ns] : batch2[ns - 512];
        int s1v = adj[(long)node * MAXDEG + col1[i]];
        s2[t2] = adj[(long)s1v * MAXDEG + col2[t2]];
        if (t2 - i * FS2 == 0) {
            s1[i] = s1v;
            if (i - ns * FS1 == 0) nodes[ns] = node;
        }
    }
}

// ---------------- fused gather means (burst loads for MLP) ----------------
template<int F>
__device__ __forceinline__ void mean_body(const float* __restrict__ src,
                                          const int* __restrict__ idx,
                                          ushort* __restrict__ dst,
                                          int g, int l)
{
    const int* ip = idx + (long)g * F;
    int r[F];
    #pragma unroll
    for (int j = 0; j < F; ++j) r[j] = ip[j];

    float4 acc[4];
    #pragma unroll
    for (int q = 0; q < 4; ++q) acc[q] = make_float4(0.f, 0.f, 0.f, 0.f);

    #pragma unroll
    for (int j0 = 0; j0 < F; j0 += 8) {
        float4 v[8];
        #pragma unroll
        for (int u = 0; u < 8; ++u)
            if (j0 + u < F)
                v[u] = *((const float4*)(src + (long)r[j0 + u] * FD) + l);
        #pragma unroll
        for (int u = 0; u < 8; ++u)
            if (j0 + u < F) {
                int q = u & 3;
                acc[q].x += v[u].x; acc[q].y += v[u].y;
                acc[q].z += v[u].z; acc[q].w += v[u].w;
            }
    }
    float s = 1.0f / F;
    float sx = (acc[0].x + acc[1].x + acc[2].x + acc[3].x) * s;
    float sy = (acc[0].y + acc[1].y + acc[2].y + acc[3].y) * s;
    float sz = (acc[0].z + acc[1].z + acc[2].z + acc[3].z) * s;
    float sw = (acc[0].w + acc[1].w + acc[2].w + acc[3].w) * s;
    uint2 o;
    o.x = (unsigned)f2bf(sx) | ((unsigned)f2bf(sy) << 16);
    o.y = (unsigned)f2bf(sz) | ((unsigned)f2bf(sw) << 16);
    *((uint2*)(dst + (long)g * FD) + l) = o;
}

__global__ void means_kernel(const float* __restrict__ features,
                             const int* __restrict__ s2, const int* __restrict__ s1,
                             ushort* __restrict__ nm2, ushort* __restrict__ nm1)
{
    int wb = blockIdx.x;
    int wave = threadIdx.x >> 6;
    int l = threadIdx.x & 63;
    if (wb < 2560) mean_body<FS2>(features, s2, nm2, wb * 4 + wave, l);
    else           mean_body<FS1>(features, s1, nm1, (wb - 2560) * 4 + wave, l);
}

// ---------------- layer-1 MFMA GEMM: wave = 16 rows x 64 cols ----------------
// wave-unit u = blockIdx.x*4+wave in [0,5632): cs = u&3 (col strip), t = u>>2:
//   t<640: h1 self (features via s1); t<1280: h1 neigh (nm2);
//   t<1344: h0 self (features via nodes); else h0 neigh (nm1). K=256, 8 steps.
__global__ void l1gemm_kernel(const float* __restrict__ features,
                              const ushort* __restrict__ nm2, const ushort* __restrict__ nm1,
                              const int* __restrict__ s1, const int* __restrict__ nodes,
                              const ushort* __restrict__ Wt_s1, const ushort* __restrict__ Wt_n1,
                              ushort* __restrict__ h1n, ushort* __restrict__ h0n)
{
    const int wave = threadIdx.x >> 6;
    const int l    = threadIdx.x & 63;
    const int m16  = l & 15;
    const int g    = l >> 4;
    int u = blockIdx.x * 4 + wave;
    const int cs = u & 3;
    int t = u >> 2;

    int self;
    const ushort* An = nullptr;
    const int* idx = nullptr;
    const ushort* Bt;
    ushort* C;
    int coff;
    if (t < 640)       { self = 1; idx = s1;    C = h1n; Bt = Wt_s1; coff = 0; }
    else if (t < 1280) { self = 0; t -= 640;  An = nm2; C = h1n; Bt = Wt_n1; coff = 256; }
    else if (t < 1344) { self = 1; t -= 1280; idx = nodes; C = h0n; Bt = Wt_s1; coff = 0; }
    else               { self = 0; t -= 1344; An = nm1; C = h0n; Bt = Wt_n1; coff = 256; }

    const int r0  = t * 16;
    const int row = r0 + m16;
    const long arow = self ? (long)idx[row] : (long)row;

    f32x4 acc[4];
    #pragma unroll
    for (int j = 0; j < 4; ++j) acc[j] = (f32x4){0.f, 0.f, 0.f, 0.f};

    #pragma unroll
    for (int k0 = 0; k0 < 256; k0 += 32) {
        bf16x8 a;
        if (self) {
            const float* p = features + arow * FD + k0 + g * 8;
            float4 v0 = *(const float4*)p;
            float4 v1 = *(const float4*)(p + 4);
            a[0] = (short)f2bf(v0.x); a[1] = (short)f2bf(v0.y);
            a[2] = (short)f2bf(v0.z); a[3] = (short)f2bf(v0.w);
            a[4] = (short)f2bf(v1.x); a[5] = (short)f2bf(v1.y);
            a[6] = (short)f2bf(v1.z); a[7] = (short)f2bf(v1.w);
        } else {
            a = *(const bf16x8*)(An + arow * FD + k0 + g * 8);
        }
        #pragma unroll
        for (int j = 0; j < 4; ++j) {
            bf16x8 bf = *(const bf16x8*)(Bt + (long)(cs * 64 + j * 16 + m16) * 256 + k0 + g * 8);
            acc[j] = __builtin_amdgcn_mfma_f32_16x16x32_bf16(a, bf, acc[j], 0, 0, 0);
        }
    }

    // D: col = lane&15, row = (lane>>4)*4 + reg  [m89-verified]
    #pragma unroll
    for (int j = 0; j < 4; ++j) {
        #pragma unroll
        for (int r = 0; r < 4; ++r) {
            int rr = r0 + g * 4 + r;
            int cc = coff + cs * 64 + j * 16 + m16;
            C[(long)rr * 512 + cc] = f2bf(fmaxf(acc[j][r], 0.f));
        }
    }
}

// ---------------- layer-2 neighbor mean (groups of 10 consecutive h1n rows) ----
__global__ void mean_bf16_kernel(const ushort* __restrict__ src,
                                 ushort* __restrict__ dst,
                                 int F, int G)
{
    int g = blockIdx.x * 4 + (threadIdx.x >> 6);
    if (g >= G) return;
    int l = threadIdx.x & 63;
    float acc[8] = {};
    for (int j = 0; j < F; ++j) {
        uint4 v = *((const uint4*)(src + ((long)g * F + j) * 512) + l);
        unsigned w[4] = { v.x, v.y, v.z, v.w };
        #pragma unroll
        for (int q = 0; q < 4; ++q) {
            acc[2 * q]     += bf2f((ushort)(w[q] & 0xFFFF));
            acc[2 * q + 1] += bf2f((ushort)(w[q] >> 16));
        }
    }
    float s = 1.0f / F;
    uint4 o;
    unsigned* ow = (unsigned*)&o;
    #pragma unroll
    for (int q = 0; q < 4; ++q)
        ow[q] = (unsigned)f2bf(acc[2 * q] * s) | ((unsigned)f2bf(acc[2 * q + 1] * s) << 16);
    *((uint4*)(dst + (long)g * 512) + l) = o;
}

// ---------------- layer-2 MFMA GEMM: wave = 16r x 64c, K-split x4 ----------------
// u = blockIdx.x*4+wave in [0,2048): kh=u&3, cs=(u>>2)&3, rt=(u>>4)&63, sub=u>>10.
// Writes fp32 partials opre[kh][1024][512]; l2norm sums the 4.
__global__ void l2gemm_kernel(const ushort* __restrict__ h0n, const ushort* __restrict__ ml2,
                              const ushort* __restrict__ Wt_s2, const ushort* __restrict__ Wt_n2,
                              float* __restrict__ opre)
{
    const int wave = threadIdx.x >> 6;
    const int l    = threadIdx.x & 63;
    const int m16  = l & 15;
    const int g    = l >> 4;
    int u = blockIdx.x * 4 + wave;
    const int kh  = u & 3;
    const int cs  = (u >> 2) & 3;
    const int rt  = (u >> 4) & 63;
    const int sub = u >> 10;

    const ushort* A  = sub ? ml2 : h0n;
    const ushort* Bt = sub ? Wt_n2 : Wt_s2;
    const int coff   = sub ? 256 : 0;

    const int r0  = rt * 16;
    const int row = r0 + m16;
    const int kb  = kh * 128;

    f32x4 acc[4];
    #pragma unroll
    for (int j = 0; j < 4; ++j) acc[j] = (f32x4){0.f, 0.f, 0.f, 0.f};

    #pragma unroll
    for (int ks = 0; ks < 128; ks += 32) {
        int k = kb + ks;
        bf16x8 a = *(const bf16x8*)(A + (long)row * 512 + k + g * 8);
        #pragma unroll
        for (int j = 0; j < 4; ++j) {
            bf16x8 bf = *(const bf16x8*)(Bt + (long)(cs * 64 + j * 16 + m16) * 512 + k + g * 8);
            acc[j] = __builtin_amdgcn_mfma_f32_16x16x32_bf16(a, bf, acc[j], 0, 0, 0);
        }
    }

    float* op = opre + (long)kh * NB2 * 512;
    #pragma unroll
    for (int j = 0; j < 4; ++j) {
        #pragma unroll
        for (int r = 0; r < 4; ++r) {
            int rr = r0 + g * 4 + r;
            int cc = coff + cs * 64 + j * 16 + m16;
            op[(long)rr * 512 + cc] = acc[j][r];
        }
    }
}

// ---------------- row L2 normalize (sums 4 K-split partials) ----------------
__global__ void l2norm_kernel(const float* __restrict__ in, float* __restrict__ out)
{
    int r = blockIdx.x;
    int t = threadIdx.x;
    long i0 = (long)r * 512 + t;
    const long P = (long)NB2 * 512;
    float v0 = in[i0]       + in[i0 + P]       + in[i0 + 2*P]       + in[i0 + 3*P];
    float v1 = in[i0 + 256] + in[i0 + P + 256] + in[i0 + 2*P + 256] + in[i0 + 3*P + 256];
    float s = v0 * v0 + v1 * v1;
    #pragma unroll
    for (int o = 32; o > 0; o >>= 1) s += __shfl_down(s, o, 64);
    __shared__ float wsum[4];
    if ((t & 63) == 0) wsum[t >> 6] = s;
    __syncthreads();
    float tot = wsum[0] + wsum[1] + wsum[2] + wsum[3];
    float inv = rsqrtf(fmaxf(tot, 1e-12f));
    out[r * 512 + t] = v0 * inv;
    out[r * 512 + 256 + t] = v1 * inv;
}

extern "C" void kernel_launch(void* const* d_in, const int* in_sizes, int n_in,
                              void* d_out, int out_size, void* d_ws, size_t ws_size,
                              hipStream_t stream)
{
    const float* features = (const float*)d_in[0];
    const float* Ws1      = (const float*)d_in[1];
    const float* Wn1      = (const float*)d_in[2];
    const float* Ws2      = (const float*)d_in[3];
    const float* Wn2      = (const float*)d_in[4];
    const int*   adj      = (const int*)d_in[5];
    const int*   batch1   = (const int*)d_in[6];
    const int*   batch2   = (const int*)d_in[7];
    const int*   col1     = (const int*)d_in[8];
    const int*   col2     = (const int*)d_in[9];
    float* out = (float*)d_out;

    char* w = (char*)d_ws;
    auto alloc = [&](size_t bytes) {
        char* p = w;
        w += (bytes + 255) & ~(size_t)255;
        return p;
    };
    int*    nodes = (int*)alloc((size_t)NB2 * 4);
    int*    s1    = (int*)alloc((size_t)NB2 * FS1 * 4);
    int*    s2    = (int*)alloc((size_t)NB2 * FS1 * FS2 * 4);
    ushort* nm1   = (ushort*)alloc((size_t)NB2 * FD * 2);            // bf16 [1024,256]
    ushort* nm2   = (ushort*)alloc((size_t)NB2 * FS1 * FD * 2);      // bf16 [10240,256]
    ushort* h0n   = (ushort*)alloc((size_t)NB2 * 512 * 2);           // bf16 [1024,512]
    ushort* h1n   = (ushort*)alloc((size_t)NB2 * FS1 * 512 * 2);     // bf16 [10240,512]
    ushort* ml2   = (ushort*)alloc((size_t)NB2 * 512 * 2);           // bf16 [1024,512]
    float*  opre  = (float*)alloc((size_t)4 * NB2 * 512 * 4);        // fp32 [4][1024][512]
    ushort* Wt_s1 = (ushort*)alloc((size_t)FD * FH * 2);             // [256][256] n-major
    ushort* Wt_n1 = (ushort*)alloc((size_t)FD * FH * 2);
    ushort* Wt_s2 = (ushort*)alloc((size_t)512 * FH * 2);            // [256][512] n-major
    ushort* Wt_n2 = (ushort*)alloc((size_t)512 * FH * 2);

    // 1. prep: weight transpose/cast + sampling (s1, s2, nodes)
    prep_kernel<<<2536, 256, 0, stream>>>(Ws1, Wn1, Ws2, Wn2,
                                          Wt_s1, Wt_n1, Wt_s2, Wt_n2,
                                          batch1, batch2, adj, col1, col2,
                                          nodes, s1, s2);

    // 2. layer-1 gather means (fp32 accumulate, bf16 out)
    means_kernel<<<2816, 256, 0, stream>>>(features, s2, s1, nm2, nm1);

    // 3. layer-1 GEMMs (relu, bf16 out) — 5632 wave-units / 1408 blocks
    l1gemm_kernel<<<1408, 256, 0, stream>>>(features, nm2, nm1, s1, nodes,
                                            Wt_s1, Wt_n1, h1n, h0n);

    // 4. layer-2 neighbor mean (groups of 10 consecutive h1n rows)
    mean_bf16_kernel<<<NB2 / 4, 256, 0, stream>>>(h1n, ml2, FS1, NB2);

    // 5. layer-2 GEMMs (identity, fp32 partials, K-split x4) — 512 blocks
    l2gemm_kernel<<<512, 256, 0, stream>>>(h0n, ml2, Wt_s2, Wt_n2, opre);

    // 6. L2 normalize (sums partials) -> output
    l2norm_kernel<<<NB2, 256, 0, stream>>>(opre, out);
}